// Round 4
// baseline (11.123 us; speedup 1.0000x reference)
//
#include <hip/hip_runtime.h>
#include <math.h>

// Reference: tr = sum_i exp(W0[i,i]^2);  out = (tr - N)^2   (scalar fp32)
// Single dispatch, 128 blocks x 1 wave: each block reduces 64 diagonal
// elements; the LAST block (atomic ticket) sums the 128 partials in fixed
// index order (deterministic) and writes the result. Ticket counter needs
// no reset: exactly one of any nb consecutive atomicAdd returns satisfies
// old % nb == nb-1, so it works from any initial value across graph replays.

__global__ __launch_bounds__(64) void diag_loss_onepass(
    const float* __restrict__ W, float* __restrict__ out,
    unsigned* __restrict__ counter, double* __restrict__ partials, int N) {
    const int lane = threadIdx.x;            // 0..63
    const int bid  = blockIdx.x;
    const int nb   = gridDim.x;
    const int i    = bid * 64 + lane;        // diagonal index
    const size_t stride = (size_t)N + 1;

    double acc = 0.0;
    if (i < N) {
        float x = W[(size_t)i * stride];
        acc = (double)expf(x * x);
    }

    #pragma unroll
    for (int off = 32; off > 0; off >>= 1)
        acc += __shfl_down(acc, off, 64);

    unsigned old = 0;
    if (lane == 0) {
        __hip_atomic_store(&partials[bid], acc,
                           __ATOMIC_RELEASE, __HIP_MEMORY_SCOPE_AGENT);
        old = __hip_atomic_fetch_add(counter, 1u,
                                     __ATOMIC_ACQ_REL, __HIP_MEMORY_SCOPE_AGENT);
    }
    old = __shfl(old, 0, 64);                 // broadcast lane0's ticket
    const bool is_last = (old % (unsigned)nb) == (unsigned)(nb - 1);

    if (is_last) {
        __threadfence();                      // acquire: see all partials
        double s = 0.0;
        for (int p = lane; p < nb; p += 64)   // fixed order -> deterministic
            s += __hip_atomic_load(&partials[p],
                                   __ATOMIC_RELAXED, __HIP_MEMORY_SCOPE_AGENT);
        #pragma unroll
        for (int off = 32; off > 0; off >>= 1)
            s += __shfl_down(s, off, 64);
        if (lane == 0) {
            double d = s - (double)N;
            out[0] = (float)(d * d);
        }
    }
}

extern "C" void kernel_launch(void* const* d_in, const int* in_sizes, int n_in,
                              void* d_out, int out_size, void* d_ws, size_t ws_size,
                              hipStream_t stream) {
    const float* W = (const float*)d_in[0];
    float* out = (float*)d_out;

    long long total = (long long)in_sizes[0];
    int N = (int)(sqrt((double)total) + 0.5);

    // d_ws layout: [0..63] ticket counter (aligned), [64..] double partials
    unsigned* counter = (unsigned*)d_ws;
    double* partials  = (double*)((char*)d_ws + 64);

    int nblocks = (N + 63) / 64;   // 128 for N=8192
    diag_loss_onepass<<<nblocks, 64, 0, stream>>>(W, out, counter, partials, N);
}

// Round 5
// 10.146 us; speedup vs baseline: 1.0962x; 1.0962x over previous
//
#include <hip/hip_runtime.h>
#include <math.h>

// Reference: tr = sum_i exp(W0[i,i]^2);  out = (tr - N)^2   (scalar fp32)
// Only the diagonal matters: 8192 strided loads + reduce -> one scalar.
// Measured floor across 4 structural variants (1-block, 128-block,
// 2-dispatch, atomic-ticket): ~10.2-11.6 us — launch/replay bound.
// Final: single minimal dispatch, 1 block x 1024 threads.

__global__ __launch_bounds__(1024) void diag_trace_loss_kernel(
    const float* __restrict__ W, float* __restrict__ out, int N) {
    const int tid = threadIdx.x;
    const size_t stride = (size_t)N + 1;  // diagonal stride in elements

    double acc = 0.0;
    for (int i = tid; i < N; i += 1024) {
        float x = W[(size_t)i * stride];
        acc += (double)expf(x * x);
    }

    // intra-wave reduction (wave = 64 lanes)
    #pragma unroll
    for (int off = 32; off > 0; off >>= 1)
        acc += __shfl_down(acc, off, 64);

    __shared__ double wave_sums[16];  // 1024/64 waves
    const int lane = tid & 63;
    const int wave = tid >> 6;
    if (lane == 0) wave_sums[wave] = acc;
    __syncthreads();

    if (wave == 0) {
        double v = (lane < 16) ? wave_sums[lane] : 0.0;
        #pragma unroll
        for (int off = 8; off > 0; off >>= 1)
            v += __shfl_down(v, off, 64);
        if (lane == 0) {
            double d = v - (double)N;
            out[0] = (float)(d * d);
        }
    }
}

extern "C" void kernel_launch(void* const* d_in, const int* in_sizes, int n_in,
                              void* d_out, int out_size, void* d_ws, size_t ws_size,
                              hipStream_t stream) {
    const float* W = (const float*)d_in[0];
    float* out = (float*)d_out;

    long long total = (long long)in_sizes[0];
    int N = (int)(sqrt((double)total) + 0.5);

    diag_trace_loss_kernel<<<1, 1024, 0, stream>>>(W, out, N);
}